// Round 5
// baseline (753.757 us; speedup 1.0000x reference)
//
#include <hip/hip_runtime.h>
#include <hip/hip_bf16.h>

#define B_ 64
#define N_ 4096
#define KS 8
#define NCH 16          // token chunks per batch (256 tokens each)
#define LNEPS 1e-5f
#define EPSA 1e-8f
#define SCALE 0.08838834764831845f   // 1/sqrt(128)

typedef short short4v __attribute__((ext_vector_type(4)));

__device__ __forceinline__ float bflo(unsigned u) {
  union { unsigned u; float f; } c; c.u = u << 16; return c.f;
}
__device__ __forceinline__ float bfhi(unsigned u) {
  union { unsigned u; float f; } c; c.u = u & 0xffff0000u; return c.f;
}
__device__ __forceinline__ unsigned fbits(float f) {
  union { float f; unsigned u; } c; c.f = f; return c.u;
}
__device__ __forceinline__ float sigmf(float x) { return 1.f / (1.f + __expf(-x)); }

// ================= prep: fused weight products + folded biases =================
__global__ __launch_bounds__(256) void prep_kernel(
    const float* __restrict__ Wih, const float* __restrict__ Whh,
    const float* __restrict__ Wq,  const float* __restrict__ Wk,
    const float* __restrict__ Wv,  const float* __restrict__ W1,
    const float* __restrict__ W2,
    const float* __restrict__ g_slot, const float* __restrict__ g_mlp,
    const float* __restrict__ bq, const float* __restrict__ bk,
    const float* __restrict__ bv, const float* __restrict__ b_ih,
    const float* __restrict__ b_hh, const float* __restrict__ b1,
    const float* __restrict__ b_mlp, const float* __restrict__ b_slot,
    float* __restrict__ WgT, float* __restrict__ Mq,
    float* __restrict__ W1gT, float* __restrict__ W2T,
    float* __restrict__ cq_vec, float* __restrict__ wqcg,
    float* __restrict__ qc0g, float* __restrict__ bg, float* __restrict__ b1f)
{
  if (blockIdx.x == 576) {           // ---- bias folds (1 block) ----
    __shared__ float u[128], wqcr[128];
    int t = threadIdx.x;
    if (t < 128) {                          // u = Wq.b_slot + bq
      float a = bq[t];
      for (int d = 0; d < 128; d++) a += Wq[t*128 + d] * b_slot[d];
      u[t] = a;
    } else {                                // wqcr = SCALE * Wq^T.bk
      int d = t - 128;
      float a = 0.f;
      for (int j = 0; j < 128; j++) a += Wq[j*128 + d] * bk[j];
      wqcr[d] = a * SCALE;
    }
    __syncthreads();
    if (t < 128) {                          // cq_vec = SCALE * Wk^T.u ; wqcg
      float a = 0.f;
      for (int j = 0; j < 128; j++) a += Wk[j*128 + t] * u[j];
      cq_vec[t] = a * SCALE;
      wqcg[t] = wqcr[t] * g_slot[t];
    } else {                                // b1f = b1 + W1.b_mlp
      int d = t - 128;
      float a = b1[d];
      for (int k = 0; k < 128; k++) a += W1[d*128 + k] * b_mlp[k];
      b1f[d] = a;
    }
    if (t < 64) {                           // qc0 = wqcr.b_slot + SCALE*bq.bk
      float v = wqcr[t]*b_slot[t] + wqcr[t+64]*b_slot[t+64]
              + SCALE*(bq[t]*bk[t] + bq[t+64]*bk[t+64]);
      #pragma unroll
      for (int st = 1; st < 64; st <<= 1) v += __shfl_xor(v, st);
      if (t == 0) *qc0g = v;
    }
    #pragma unroll
    for (int p = 0; p < 3; p++) {           // bg: folded GRU bias (i-side absorbs bv)
      int j = t + p*256;
      if (j < 384) {
        float a = b_ih[j];
        for (int k = 0; k < 128; k++) a += Wih[j*128 + k] * bv[k];
        bg[j] = a;
      } else if (j < 768) {
        bg[j] = b_hh[j - 384];
      }
    }
    return;
  }
  int id = blockIdx.x * 256 + threadIdx.x;
  if (id < 49152) {                       // (Wih.Wv) into WgT cols 0..383
    int j = id >> 7, d = id & 127;
    float a = 0.f;
    for (int k = 0; k < 128; k++) a += Wih[j*128 + k] * Wv[k*128 + d];
    WgT[d*768 + j] = a;
  } else if (id < 65536) {                // Mq = SCALE*g_slot[d]*(Wk^T.Wq)[t][d]
    int k = id - 49152; int d = k >> 7, t = k & 127;
    float a = 0.f;
    for (int j = 0; j < 128; j++) a += Wk[j*128 + t] * Wq[j*128 + d];
    Mq[d*128 + t] = a * SCALE * g_slot[d];
  } else if (id < 114688) {               // Whh^T into WgT cols 384..767
    int k = id - 65536; int j = k >> 7, d = k & 127;
    WgT[d*768 + 384 + j] = Whh[j*128 + d];
  } else if (id < 131072) {               // W1gT (g_mlp folded)
    int k = id - 114688; int t = k >> 7, d = k & 127;
    W1gT[d*128 + t] = W1[t*128 + d] * g_mlp[d];
  } else if (id < 147456) {               // W2T
    int k = id - 131072; int t = k >> 7, d = k & 127;
    W2T[d*128 + t] = W2[t*128 + d];
  }
}

// ================= q_init: qt/qc from slots_init via precomputed Mq =================
__global__ __launch_bounds__(64) void q_init_kernel(
    const float* __restrict__ slots_in, const float* __restrict__ Mq,
    const float* __restrict__ cq_vec, const float* __restrict__ wqcg,
    const float* __restrict__ qc0g,
    float* __restrict__ qt, float* __restrict__ qc)
{
  __shared__ float lnr[128];
  int row = blockIdx.x, t = threadIdx.x;   // one wave
  float a = slots_in[row*128 + t], b = slots_in[row*128 + 64 + t];
  float s = a + b, s2 = a*a + b*b;
  #pragma unroll
  for (int st = 1; st < 64; st <<= 1) { s += __shfl_xor(s, st); s2 += __shfl_xor(s2, st); }
  float mean = s * (1.f/128.f);
  float rstd = rsqrtf(s2 * (1.f/128.f) - mean*mean + LNEPS);
  lnr[t] = (a - mean)*rstd; lnr[t+64] = (b - mean)*rstd;
  __syncthreads();
  float a0 = cq_vec[t], a1 = cq_vec[t+64];
  for (int d = 0; d < 128; d++) {
    float l = lnr[d];
    a0 += Mq[d*128 + t] * l;
    a1 += Mq[d*128 + 64 + t] * l;
  }
  qt[row*128 + t] = a0; qt[row*128 + 64 + t] = a1;
  float vq = wqcg[t]*lnr[t] + wqcg[t+64]*lnr[t+64];
  #pragma unroll
  for (int st = 1; st < 64; st <<= 1) vq += __shfl_xor(vq, st);
  if (t == 0) qc[row] = vq + *qc0g;
}

// ====== per-token-step core: dots -> softmax -> U/S accumulate (registers only) ======
// 16 lanes per token; lane owns dims c*8..c*8+7 (vf). qv = q~ for its dims.
__device__ __forceinline__ void attn_token_step(
    const float vf[8], const float qv[8][8], const float qcr[8],
    float u[8][8], float* sacc)
{
  float lg[8];
  #pragma unroll
  for (int s8 = 0; s8 < 8; s8++) {
    float p = qv[s8][0]*vf[0];
    #pragma unroll
    for (int j = 1; j < 8; j++) p += qv[s8][j]*vf[j];
    p += __shfl_xor(p, 1);
    p += __shfl_xor(p, 2);
    p += __shfl_xor(p, 4);
    p += __shfl_xor(p, 8);
    lg[s8] = p + qcr[s8];
  }
  float mx = lg[0];
  #pragma unroll
  for (int s8 = 1; s8 < 8; s8++) mx = fmaxf(mx, lg[s8]);
  float e[8], den = 0.f;
  #pragma unroll
  for (int s8 = 0; s8 < 8; s8++) { e[s8] = __expf(lg[s8]-mx); den += e[s8]; }
  float rd = 1.f/den;
  #pragma unroll
  for (int s8 = 0; s8 < 8; s8++) {
    float p = e[s8]*rd + EPSA;
    sacc[s8] += p;
    #pragma unroll
    for (int j = 0; j < 8; j++) u[s8][j] += p*vf[j];
  }
}

__device__ __forceinline__ void load_q(
    const float* __restrict__ qt, const float* __restrict__ qc,
    int batch, int c, float qv[8][8], float qcr[8])
{
  #pragma unroll
  for (int s8 = 0; s8 < 8; s8++) {
    float4 qa = *(const float4*)(qt + (batch*KS + s8)*128 + c*8);
    float4 qb = *(const float4*)(qt + (batch*KS + s8)*128 + c*8 + 4);
    qv[s8][0]=qa.x; qv[s8][1]=qa.y; qv[s8][2]=qa.z; qv[s8][3]=qa.w;
    qv[s8][4]=qb.x; qv[s8][5]=qb.y; qv[s8][6]=qb.z; qv[s8][7]=qb.w;
    qcr[s8] = qc[batch*KS + s8];
  }
}

// ================= epilogue: block-level U/S reduction =================
__device__ __forceinline__ void attn_epilogue(
    float u[8][8], float* sacc, float* uredf /*[4*1024]*/, float (*sred)[8],
    int tid, int w, int lane, int chunk, int batch,
    float* __restrict__ Upart, float* __restrict__ Spart)
{
  #pragma unroll
  for (int s8 = 0; s8 < 8; s8++) {
    #pragma unroll
    for (int j = 0; j < 8; j++) {
      float v = u[s8][j];
      v += __shfl_xor(v, 16);
      v += __shfl_xor(v, 32);
      u[s8][j] = v;
    }
    float sv = sacc[s8];          // identical within 16-lane group; sum over tg only
    sv += __shfl_xor(sv, 16);
    sv += __shfl_xor(sv, 32);
    if (lane == 0) sred[w][s8] = sv;
  }
  if (lane < 16) {
    float* uw = uredf + w*1024;
    #pragma unroll
    for (int s8 = 0; s8 < 8; s8++) {
      float4 A; A.x=u[s8][0]; A.y=u[s8][1]; A.z=u[s8][2]; A.w=u[s8][3];
      float4 Bv; Bv.x=u[s8][4]; Bv.y=u[s8][5]; Bv.z=u[s8][6]; Bv.w=u[s8][7];
      *(float4*)&uw[s8*128 + lane*8]     = A;
      *(float4*)&uw[s8*128 + lane*8 + 4] = Bv;
    }
  }
  __syncthreads();
  {
    int i4 = tid * 4;
    float4 a = *(const float4*)(uredf + i4);
    float4 b = *(const float4*)(uredf + 1024 + i4);
    float4 c = *(const float4*)(uredf + 2048 + i4);
    float4 d = *(const float4*)(uredf + 3072 + i4);
    float4 o4;
    o4.x = a.x+b.x+c.x+d.x; o4.y = a.y+b.y+c.y+d.y;
    o4.z = a.z+b.z+c.z+d.z; o4.w = a.w+b.w+c.w+d.w;
    *(float4*)(Upart + (size_t)(batch*NCH + chunk)*1024 + i4) = o4;
    if (tid < 8)
      Spart[(batch*NCH + chunk)*8 + tid] =
        sred[0][tid] + sred[1][tid] + sred[2][tid] + sred[3][tid];
  }
}

// ================= attn (iters 1/2): contiguous int4 stream, 4-deep prefetch =====
__global__ __launch_bounds__(256, 2) void attn_kernel(
    const unsigned short* __restrict__ xn,
    const float* __restrict__ qt, const float* __restrict__ qc,
    float* __restrict__ Upart, float* __restrict__ Spart)
{
  __shared__ float ured[4096];
  __shared__ float sred[4][8];
  const int tid = threadIdx.x;
  const int w = tid >> 6, lane = tid & 63;
  const int c = lane & 15;                 // dim chunk
  const int chunk = blockIdx.x, batch = blockIdx.y;

  float qv[8][8], qcr[8];
  load_q(qt, qc, batch, c, qv, qcr);

  float u[8][8], sacc[8];
  #pragma unroll
  for (int s8 = 0; s8 < 8; s8++) {
    sacc[s8] = 0.f;
    #pragma unroll
    for (int j = 0; j < 8; j++) u[s8][j] = 0.f;
  }

  // wave w streams 64 tokens in 16 steps of 4; int4/lane = contiguous 1KB/instr
  const int4* xb = (const int4*)(xn + ((size_t)batch*N_ + chunk*256 + w*64)*128);
  int4 buf[4];
  #pragma unroll
  for (int i = 0; i < 4; i++) buf[i] = xb[i*64 + lane];

  #pragma unroll
  for (int s = 0; s < 16; s++) {
    int4 cur = buf[s & 3];
    if (s < 12) buf[s & 3] = xb[(s+4)*64 + lane];
    float vf[8];
    unsigned d0 = (unsigned)cur.x, d1 = (unsigned)cur.y,
             d2 = (unsigned)cur.z, d3 = (unsigned)cur.w;
    vf[0] = bflo(d0); vf[1] = bfhi(d0);
    vf[2] = bflo(d1); vf[3] = bfhi(d1);
    vf[4] = bflo(d2); vf[5] = bfhi(d2);
    vf[6] = bflo(d3); vf[7] = bfhi(d3);
    attn_token_step(vf, qv, qcr, u, sacc);
  }
  attn_epilogue(u, sacc, ured, sred, tid, w, lane, chunk, batch, Upart, Spart);
}

// ================= attn0 (iter 0): fused LN + attention, writes xn =================
__global__ __launch_bounds__(256, 2) void attn0_kernel(
    const float* __restrict__ x, const float* __restrict__ g_in, const float* __restrict__ b_in,
    unsigned short* __restrict__ xn,
    const float* __restrict__ qt, const float* __restrict__ qc,
    float* __restrict__ Upart, float* __restrict__ Spart)
{
  __shared__ float ured[4096];
  __shared__ float sred[4][8];
  const int tid = threadIdx.x;
  const int w = tid >> 6, lane = tid & 63;
  const int c = lane & 15, tg = lane >> 4;
  const int chunk = blockIdx.x, batch = blockIdx.y;

  float qv[8][8], qcr[8];
  load_q(qt, qc, batch, c, qv, qcr);
  float4 gA = *(const float4*)(g_in + c*8), gB = *(const float4*)(g_in + c*8 + 4);
  float4 bA = *(const float4*)(b_in + c*8), bB = *(const float4*)(b_in + c*8 + 4);

  float u[8][8], sacc[8];
  #pragma unroll
  for (int s8 = 0; s8 < 8; s8++) {
    sacc[s8] = 0.f;
    #pragma unroll
    for (int j = 0; j < 8; j++) u[s8][j] = 0.f;
  }

  const size_t tok0 = (size_t)batch*N_ + chunk*256 + w*64;
  const float* xg0 = x + (tok0 + tg)*128 + c*8;     // step s: + s*512 floats
  unsigned short* xnw = xn + (tok0 + tg)*128 + c*8; // step s: + s*512 elems

  float4 bufa[2], bufb[2];
  #pragma unroll
  for (int i = 0; i < 2; i++) {
    bufa[i] = *(const float4*)(xg0 + i*512);
    bufb[i] = *(const float4*)(xg0 + i*512 + 4);
  }

  #pragma unroll
  for (int s = 0; s < 16; s++) {
    float4 va = bufa[s & 1], vb = bufb[s & 1];
    if (s < 14) {
      bufa[s & 1] = *(const float4*)(xg0 + (s+2)*512);
      bufb[s & 1] = *(const float4*)(xg0 + (s+2)*512 + 4);
    }
    float sm  = va.x + va.y + va.z + va.w + vb.x + vb.y + vb.z + vb.w;
    float sq  = va.x*va.x + va.y*va.y + va.z*va.z + va.w*va.w
              + vb.x*vb.x + vb.y*vb.y + vb.z*vb.z + vb.w*vb.w;
    sm += __shfl_xor(sm, 1); sq += __shfl_xor(sq, 1);
    sm += __shfl_xor(sm, 2); sq += __shfl_xor(sq, 2);
    sm += __shfl_xor(sm, 4); sq += __shfl_xor(sq, 4);
    sm += __shfl_xor(sm, 8); sq += __shfl_xor(sq, 8);
    float mean = sm * (1.f/128.f);
    float rstd = rsqrtf(sq * (1.f/128.f) - mean*mean + LNEPS);
    float nf[8];
    nf[0] = (va.x - mean)*rstd*gA.x + bA.x;
    nf[1] = (va.y - mean)*rstd*gA.y + bA.y;
    nf[2] = (va.z - mean)*rstd*gA.z + bA.z;
    nf[3] = (va.w - mean)*rstd*gA.w + bA.w;
    nf[4] = (vb.x - mean)*rstd*gB.x + bB.x;
    nf[5] = (vb.y - mean)*rstd*gB.y + bB.y;
    nf[6] = (vb.z - mean)*rstd*gB.z + bB.z;
    nf[7] = (vb.w - mean)*rstd*gB.w + bB.w;
    // pack to bf16 (truncate) via v_perm: low short = even dim, high = odd dim
    int4 st;
    st.x = (int)__builtin_amdgcn_perm(fbits(nf[1]), fbits(nf[0]), 0x07060302u);
    st.y = (int)__builtin_amdgcn_perm(fbits(nf[3]), fbits(nf[2]), 0x07060302u);
    st.z = (int)__builtin_amdgcn_perm(fbits(nf[5]), fbits(nf[4]), 0x07060302u);
    st.w = (int)__builtin_amdgcn_perm(fbits(nf[7]), fbits(nf[6]), 0x07060302u);
    *(int4*)(xnw + s*512) = st;
    attn_token_step(nf, qv, qcr, u, sacc);
  }
  attn_epilogue(u, sacc, ured, sred, tid, w, lane, chunk, batch, Upart, Spart);
}

// ================= per-slot-row update (shortened chain) =================
__global__ __launch_bounds__(256) void update_kernel(
    const float* __restrict__ slots_in, float* __restrict__ slots_out,
    const float* __restrict__ Upart, const float* __restrict__ Spart,
    const float* __restrict__ WgT, const float* __restrict__ bg,
    const float* __restrict__ W1gT, const float* __restrict__ b1f,
    const float* __restrict__ W2T, const float* __restrict__ b2,
    const float* __restrict__ Mq, const float* __restrict__ cq_vec,
    const float* __restrict__ wqcg, const float* __restrict__ qc0g,
    float* __restrict__ qt, float* __restrict__ qc)
{
  __shared__ float bu[128], hb[128], gg[768];
  __shared__ float s1[128], lnr[128], hmv[128], s2v[128], lnr2[128];
  __shared__ float stats[2], sSum;
  int row = blockIdx.x, t = threadIdx.x;
  int batch = row >> 3, slot = row & 7;

  float usum = 0.f;
  if (t < 128) {
    const float* Up = Upart + ((size_t)(batch*NCH)*8 + slot)*128 + t;
    #pragma unroll
    for (int c = 0; c < NCH; c++) usum += Up[(size_t)c*1024];
  } else {
    hb[t-128] = slots_in[row*128 + (t-128)];
    if (t < 192) {
      int l2 = t - 128;
      float sv = (l2 < NCH) ? Spart[(batch*NCH + l2)*8 + slot] : 0.f;
      #pragma unroll
      for (int st = 1; st < 16; st <<= 1) sv += __shfl_xor(sv, st);
      if (l2 == 0) sSum = sv;
    }
  }
  __syncthreads();
  if (t < 128) bu[t] = usum / sSum;
  __syncthreads();
  {  // GRU gemv over combined WgT[128][768] (i-side absorbs Wv)
    float a0 = bg[t], a1 = bg[t+256], a2 = bg[t+512];
    const float* v1p = (t < 128) ? bu : hb;
    for (int d = 0; d < 128; d++) {
      float sd = bu[d], hd = hb[d], vd = v1p[d];
      const float* wr = WgT + d*768 + t;
      a0 += sd * wr[0];
      a1 += vd * wr[256];
      a2 += hd * wr[512];
    }
    gg[t] = a0; gg[t+256] = a1; gg[t+512] = a2;
  }
  __syncthreads();
  if (t < 128) {
    float r = sigmf(gg[t] + gg[384+t]);
    float z = sigmf(gg[128+t] + gg[512+t]);
    float n = tanhf(gg[256+t] + r * gg[640+t]);
    s1[t] = (1.f - z)*n + z*hb[t];
  }
  __syncthreads();
  if (t < 64) {
    float a = s1[t], b = s1[t+64];
    float s = a + b, s2 = a*a + b*b;
    #pragma unroll
    for (int st = 1; st < 64; st <<= 1) { s += __shfl_xor(s, st); s2 += __shfl_xor(s2, st); }
    if (t == 0) { float mean = s*(1.f/128.f); stats[0] = mean;
                  stats[1] = rsqrtf(s2*(1.f/128.f) - mean*mean + LNEPS); }
  }
  __syncthreads();
  if (t < 128) lnr[t] = (s1[t] - stats[0])*stats[1];
  __syncthreads();
  if (t < 128) {
    float a = b1f[t];
    for (int d = 0; d < 128; d++) a += W1gT[d*128 + t]*lnr[d];
    hmv[t] = fmaxf(a, 0.f);
  }
  __syncthreads();
  if (t < 128) {
    float a = s1[t] + b2[t];
    for (int d = 0; d < 128; d++) a += W2T[d*128 + t]*hmv[d];
    s2v[t] = a;
    slots_out[row*128 + t] = a;
  }
  __syncthreads();
  if (t < 64) {
    float a = s2v[t], b = s2v[t+64];
    float s = a + b, s2 = a*a + b*b;
    #pragma unroll
    for (int st = 1; st < 64; st <<= 1) { s += __shfl_xor(s, st); s2 += __shfl_xor(s2, st); }
    if (t == 0) { float mean = s*(1.f/128.f); stats[0] = mean;
                  stats[1] = rsqrtf(s2*(1.f/128.f) - mean*mean + LNEPS); }
  }
  __syncthreads();
  if (t < 128) lnr2[t] = (s2v[t] - stats[0])*stats[1];
  __syncthreads();
  if (t < 128) {
    float a = cq_vec[t];
    for (int d = 0; d < 128; d++) a += Mq[d*128 + t]*lnr2[d];
    qt[row*128 + t] = a;
  }
  if (t < 64) {
    float v = wqcg[t]*lnr2[t] + wqcg[t+64]*lnr2[t+64];
    #pragma unroll
    for (int st = 1; st < 64; st <<= 1) v += __shfl_xor(v, st);
    if (t == 0) qc[row] = v + *qc0g;
  }
}

extern "C" void kernel_launch(void* const* d_in, const int* in_sizes, int n_in,
                              void* d_out, int out_size, void* d_ws, size_t ws_size,
                              hipStream_t stream) {
  const float* x          = (const float*)d_in[0];
  const float* slots_init = (const float*)d_in[1];
  const float* Wq   = (const float*)d_in[2];
  const float* bq   = (const float*)d_in[3];
  const float* Wk   = (const float*)d_in[4];
  const float* bk   = (const float*)d_in[5];
  const float* Wv   = (const float*)d_in[6];
  const float* bv   = (const float*)d_in[7];
  const float* g_in = (const float*)d_in[8];
  const float* b_in = (const float*)d_in[9];
  const float* g_slot = (const float*)d_in[10];
  const float* b_slot = (const float*)d_in[11];
  const float* g_mlp  = (const float*)d_in[12];
  const float* b_mlp  = (const float*)d_in[13];
  const float* W1   = (const float*)d_in[14];
  const float* b1   = (const float*)d_in[15];
  const float* W2   = (const float*)d_in[16];
  const float* b2   = (const float*)d_in[17];
  const float* Wih  = (const float*)d_in[18];
  const float* Whh  = (const float*)d_in[19];
  const float* b_ih = (const float*)d_in[20];
  const float* b_hh = (const float*)d_in[21];

  char* p = (char*)d_ws;
  unsigned short* xn = (unsigned short*)p; p += (size_t)B_*N_*128*2;   // 64 MB
  float* qt    = (float*)p; p += (size_t)B_*KS*128*4;
  float* qc    = (float*)p; p += (size_t)B_*KS*4 + 1024;
  float* slots = (float*)p; p += (size_t)B_*KS*128*4;
  float* Upart = (float*)p; p += (size_t)B_*NCH*KS*128*4;              // 4 MB
  float* Spart = (float*)p; p += (size_t)B_*NCH*KS*4 + 1024;
  float* WgT   = (float*)p; p += 98304*4;
  float* Mq    = (float*)p; p += 16384*4;
  float* W1gT  = (float*)p; p += 16384*4;
  float* W2T   = (float*)p; p += 16384*4;
  float* cq_vec= (float*)p; p += 128*4;
  float* wqcg  = (float*)p; p += 128*4;
  float* qc0g  = (float*)p; p += 256;
  float* bg    = (float*)p; p += 768*4;
  float* b1f   = (float*)p; p += 128*4;

  prep_kernel<<<577, 256, 0, stream>>>(Wih, Whh, Wq, Wk, Wv, W1, W2, g_slot, g_mlp,
                                       bq, bk, bv, b_ih, b_hh, b1, b_mlp, b_slot,
                                       WgT, Mq, W1gT, W2T, cq_vec, wqcg, qc0g, bg, b1f);
  q_init_kernel<<<512, 64, 0, stream>>>(slots_init, Mq, cq_vec, wqcg, qc0g, qt, qc);

  attn0_kernel<<<dim3(NCH, B_), 256, 0, stream>>>(x, g_in, b_in, xn, qt, qc, Upart, Spart);
  update_kernel<<<512, 256, 0, stream>>>(slots_init, slots, Upart, Spart,
      WgT, bg, W1gT, b1f, W2T, b2, Mq, cq_vec, wqcg, qc0g, qt, qc);

  attn_kernel<<<dim3(NCH, B_), 256, 0, stream>>>(xn, qt, qc, Upart, Spart);
  update_kernel<<<512, 256, 0, stream>>>(slots, slots, Upart, Spart,
      WgT, bg, W1gT, b1f, W2T, b2, Mq, cq_vec, wqcg, qc0g, qt, qc);

  attn_kernel<<<dim3(NCH, B_), 256, 0, stream>>>(xn, qt, qc, Upart, Spart);
  update_kernel<<<512, 256, 0, stream>>>(slots, (float*)d_out, Upart, Spart,
      WgT, bg, W1gT, b1f, W2T, b2, Mq, cq_vec, wqcg, qc0g, qt, qc);

  (void)in_sizes; (void)n_in; (void)out_size; (void)ws_size;
}